// Round 15
// baseline (27.141 us; speedup 1.0000x reference)
//
#include <hip/hip_runtime.h>

#define Bn   4
#define CIN  32
#define COUT 32
#define CG   8
#define Hh   128
#define Ww   128
#define KK   5
#define HW   (Hh * Ww)

// fallback geometry (64x4)
#define TW   64
#define TH   4
#define PRW  68
#define PRH  8
#define NSLOT (PRW * PRH)   // 544

// main-kernel geometry (64x2)
#define T3W  64
#define T3H  2
#define P3W  68
#define P3H  6
#define N3SLOT (P3W * P3H)  // 408

typedef _Float16 h8  __attribute__((ext_vector_type(8)));
typedef _Float16 h2  __attribute__((ext_vector_type(2)));
typedef float    f4  __attribute__((ext_vector_type(4)));

// fallback LDS layout (64x4)
#define XOFF  0
#define XJG   8704
#define WOFF  34816
#define KOFF  60416
#define SMEMB 73216

// main-kernel LDS (64x2), 58.2 KB -> 2 blocks/CU:
//   x:    [4 jg][408 slot] h8 (plane stride padded) : 26240
//   w h0: [25 t][4 jg][16 o] h8                     : 25600
//   kern: [25 t][4 pg][16 pi][2 ps] f16             :  6400
#define X3JG  6560          // 408*16 + 32 pad
#define W3OFF 26240
#define K3OFF 51840
#define SMEM3 58240

// workspace (bytes)
#define XT_OFF 0                       // 4*16384*32*2 = 4,194,304
#define WT_OFF 4194304                 // 25600*2      =    51,200
#define GT_OFF 4245504                 // 4*16384*8*2  = 1,048,576
#define WS_NEED 5294080

// ---------- pre-pass: x/w/guide layout transforms ----------
__global__ __launch_bounds__(512) void prep(
    const float* __restrict__ x, const float* __restrict__ guide,
    const float* __restrict__ w,
    _Float16* __restrict__ xt, _Float16* __restrict__ wt, _Float16* __restrict__ gt)
{
    const int bid = blockIdx.x;
    const int tid = threadIdx.x;

    if (bid < 512) {
        // x[b][j][m][n] f32 -> xt[b][m][n][32j] f16
        const int b = bid >> 7, m = bid & 127;
        const int n = tid & 127, jh = tid >> 7;
        const float* xp = x + ((size_t)(b * CIN + jh * 8)) * HW + m * Ww + n;
        h8 v;
#pragma unroll
        for (int e = 0; e < 8; ++e) v[e] = (_Float16)xp[(size_t)e * HW];
        ((h8*)xt)[((size_t)b * HW + m * Ww + n) * 4 + jh] = v;
    } else if (bid < 562) {
        // w -> wt[half][t][jg][o][e] f16
        const int idx = (bid - 512) * 512 + tid;
        const int ht = idx >> 9;
        const int half = ht / 25, t = ht - half * 25;
        const int rem = idx & 511;
        const int jg = rem >> 7, o = (rem >> 3) & 15, e = rem & 7;
        wt[idx] = (_Float16)w[(size_t)(half * 16 + o) * (CIN * KK * KK) + (jg * 8 + e) * (KK * KK) + t];
    } else {
        // guide[b][c][m][n] f32 -> gt[b][m][n][8c] f16
        const int gr = (bid - 562) * 4 + (tid >> 7);
        const int b = gr >> 7, m = gr & 127;
        const int n = tid & 127;
        const float* gp = guide + ((size_t)b * CG) * HW + m * Ww + n;
        h8 v;
#pragma unroll
        for (int e = 0; e < 8; ++e) v[e] = (_Float16)gp[(size_t)e * HW];
        ((h8*)gt)[(size_t)b * HW + m * Ww + n] = v;
    }
}

// ---------- main: 64x2 o-merged tiles, 2 blocks/CU co-resident ----------
__global__ __launch_bounds__(256, 2) void pac_mfma9(
    const _Float16* __restrict__ xt, const _Float16* __restrict__ wt,
    const _Float16* __restrict__ gt, const float* __restrict__ bias,
    float* __restrict__ out)
{
    __shared__ __align__(16) unsigned char smem[SMEM3];

    const int tid = threadIdx.x;
    const int bx  = blockIdx.x;        // 0..127: 64 row-bands x 2 col-tiles
    const int bz  = blockIdx.y;        // batch
    const int tm = (bx >> 1) * T3H;
    const int tn = (bx & 1) * T3W;

    const int lane = tid & 63;
    const int l15 = lane & 15, kg = lane >> 4;

    // ---- stage x: 408 slots x 4 j-octets, b128 in / b128 out ----
    const int pxbase = bz * HW;
#pragma unroll
    for (int it = 0; it < 7; ++it) {
        const int idx = it * 256 + tid;            // over 1632 = 408*4
        if (idx < 1632) {
            const int slot = idx >> 2, jg = idx & 3;
            const int r = slot / P3W, c = slot - r * P3W;
            const int gm = tm + r - 2, gn = tn + c - 2;
            h8 v = {};
            if ((unsigned)gm < (unsigned)Hh && (unsigned)gn < (unsigned)Ww)
                v = *(const h8*)(xt + ((size_t)(pxbase + gm * Ww + gn)) * 32 + jg * 8);
            *(h8*)(smem + jg * X3JG + slot * 16) = v;
        }
    }

    // ---- stage w half0: linear b128 copy (half1 comes from global in-loop) ----
    const h8* wth = (const h8*)wt;
#pragma unroll
    for (int it = 0; it < 7; ++it) {
        const int idx = it * 256 + tid;            // over 1600 h8
        if (idx < 1600)
            *(h8*)(smem + W3OFF + idx * 16) = wth[idx];
    }

    // ---- kern in-main: f16 gt reads (L2-hot), f32 math, pair layout ----
    {
        const int px = tid & 127, th = tid >> 7;   // th=0: taps 0..12, th=1: 13..24
        const int pr = px >> 6, pc = px & 63;
        const int pg = px >> 5, ps = (px >> 4) & 1, pi = px & 15;
        const int m = tm + pr, n = tn + pc;
        const h8* gtb = (const h8*)gt + (size_t)bz * HW;
        const h8 c8 = gtb[m * Ww + n];
        float cg[8];
#pragma unroll
        for (int i = 0; i < 8; ++i) cg[i] = (float)c8[i];
        int t = 0;
#pragma unroll
        for (int k = 0; k < KK; ++k) {
#pragma unroll
            for (int l = 0; l < KK; ++l) {
                if ((t < 13) == (th == 0)) {
                    const int gm = m + k - 2, gn = n + l - 2;
                    h8 gv = {};
                    if ((unsigned)gm < (unsigned)Hh && (unsigned)gn < (unsigned)Ww)
                        gv = gtb[gm * Ww + gn];
                    float ss = 0.f;
#pragma unroll
                    for (int i = 0; i < 8; ++i) {
                        const float d = (float)gv[i] - cg[i];
                        ss = fmaf(d, d, ss);
                    }
                    // pair (pg*32+pi, pg*32+16+pi)
                    *(_Float16*)(smem + K3OFF + t * 256 + pg * 64 + pi * 4 + ps * 2) =
                        (_Float16)__expf(-0.5f * ss);
                }
                ++t;
            }
        }
    }

    __syncthreads();

    // ---- main loop: A/B0/kern from LDS, B1 from global, 4 MFMA chains ----
    const int wv = tid >> 6;                   // 4 waves
    const int st0 = wv * 32, st1 = st0 + 16;   // two 16-px M-subtiles
    const int r0 = wv >> 1;                    // tile row 0..1
    const int c00 = (wv & 1) * 32;             // col base 0/32

    f4 acc00 = {0.f,0.f,0.f,0.f}, acc01 = {0.f,0.f,0.f,0.f};
    f4 acc10 = {0.f,0.f,0.f,0.f}, acc11 = {0.f,0.f,0.f,0.f};
    const unsigned char* xg = smem + kg * X3JG;
    const int kbase = K3OFF + wv * 64 + l15 * 4;    // this lane's kern pair column
    const h8* wb1 = (const h8*)wt + 1600 + kg * 16 + l15;  // half1 fragment column

    int t = 0;
#pragma unroll
    for (int k = 0; k < KK; ++k) {
#pragma unroll
        for (int l = 0; l < KK; ++l) {
            const int abase = ((r0 + k) * P3W + c00 + l + l15) * 16;
            h8 A0 = *(const h8*)(xg + abase);
            h8 A1 = *(const h8*)(xg + abase + 256);        // +16 cols
            h8 B0 = *(const h8*)(smem + W3OFF + t * 1024 + kg * 256 + l15 * 16);
            h8 B1 = wb1[t * 64];
            h2 kk = *(const h2*)(smem + kbase + t * 256);  // (kern[px0], kern[px1])

            h8 A0s = A0 * kk[0];                           // v_pk_mul_f16
            h8 A1s = A1 * kk[1];

            acc00 = __builtin_amdgcn_mfma_f32_16x16x32_f16(A0s, B0, acc00, 0, 0, 0);
            acc01 = __builtin_amdgcn_mfma_f32_16x16x32_f16(A0s, B1, acc01, 0, 0, 0);
            acc10 = __builtin_amdgcn_mfma_f32_16x16x32_f16(A1s, B0, acc10, 0, 0, 0);
            acc11 = __builtin_amdgcn_mfma_f32_16x16x32_f16(A1s, B1, acc11, 0, 0, 0);
            ++t;
        }
    }

    const float bv0 = bias[l15], bv1 = bias[16 + l15];
#pragma unroll
    for (int i = 0; i < 4; ++i) {
        acc00[i] += bv0; acc10[i] += bv0;
        acc01[i] += bv1; acc11[i] += bv1;
    }

    // ---- transpose through LDS (aliases x region) for dense stores ----
    __syncthreads();
    float* outst = (float*)smem;               // [32 o][132 px] f32 = 16896 B
    *(f4*)(outst + l15 * 132 + st0 + kg * 4) = acc00;
    *(f4*)(outst + l15 * 132 + st1 + kg * 4) = acc10;
    *(f4*)(outst + (16 + l15) * 132 + st0 + kg * 4) = acc01;
    *(f4*)(outst + (16 + l15) * 132 + st1 + kg * 4) = acc11;
    __syncthreads();

    const int o = tid >> 3;                    // 0..31
    const int i = tid & 7;
    const int px0 = i * 16;                    // 16 px = 4 f4 per thread
    const int row = px0 >> 6, col = px0 & 63;
    float* op = out + ((size_t)(bz * COUT + o)) * HW + (size_t)(tm + row) * Ww + tn + col;
    const float* src = outst + o * 132 + px0;
#pragma unroll
    for (int c = 0; c < 4; ++c)
        *(f4*)(op + c * 4) = *(const f4*)(src + c * 4);
}

// ---------- fallback (R6 kernel, used only if ws_size too small) ----------
typedef _Float16 h4v __attribute__((ext_vector_type(4)));
__global__ __launch_bounds__(512, 4) void pac_mfma2(
    const float* __restrict__ x, const float* __restrict__ guide,
    const float* __restrict__ weight, const float* __restrict__ bias,
    float* __restrict__ out)
{
    __shared__ __align__(16) unsigned char smem[SMEMB];
    const int tid  = threadIdx.x;
    const int bx   = blockIdx.x;
    const int half = blockIdx.y;
    const int bz   = blockIdx.z;
    const int tm = (bx >> 1) * TH;
    const int tn = (bx & 1) * TW;

    const float* xb = x + (size_t)bz * CIN * HW;
#pragma unroll
    for (int it = 0; it < 34; ++it) {
        const int idx  = it * 512 + tid;
        const int j    = idx / NSLOT;
        const int slot = idx - j * NSLOT;
        const int r    = slot / PRW;
        const int c    = slot - r * PRW;
        const int gm = tm + r - 2, gn = tn + c - 2;
        float v = 0.f;
        if ((unsigned)gm < (unsigned)Hh && (unsigned)gn < (unsigned)Ww)
            v = xb[(size_t)j * HW + gm * Ww + gn];
        *(_Float16*)(smem + XOFF + (j >> 3) * XJG + slot * 16 + (j & 7) * 2) = (_Float16)v;
    }
#pragma unroll
    for (int it = 0; it < 25; ++it) {
        const int idx = it * 512 + tid;
        const int o = idx & 15;
        const int j = (idx >> 4) & 31;
        const int t = idx >> 9;
        const float v = weight[(size_t)(half * 16 + o) * (CIN * KK * KK) + j * (KK * KK) + t];
        *(_Float16*)(smem + WOFF + t * 1024 + (j >> 3) * 256 + o * 16 + (j & 7) * 2) = (_Float16)v;
    }
    {
        const int px = tid & 255, th = tid >> 8;
        const int pr = px >> 6, pc = px & 63;
        const int m = tm + pr, n = tn + pc;
        const float* gb = guide + ((size_t)bz * CG) * HW + m * Ww + n;
        float center[CG];
#pragma unroll
        for (int c = 0; c < CG; ++c) center[c] = gb[c * HW];
        int t = 0;
#pragma unroll
        for (int k = 0; k < KK; ++k) {
            const int dm = k - 2;
            const bool rowok = ((unsigned)(m + dm) < (unsigned)Hh);
#pragma unroll
            for (int l = 0; l < KK; ++l) {
                if ((t < 13) == (th == 0)) {
                    const int dn = l - 2;
                    const bool ok = rowok && ((unsigned)(n + dn) < (unsigned)Ww);
                    float ss = 0.f;
#pragma unroll
                    for (int c = 0; c < CG; ++c) {
                        float gv = ok ? gb[c * HW + dm * Ww + dn] : 0.f;
                        float d = gv - center[c];
                        ss = fmaf(d, d, ss);
                    }
                    *(_Float16*)(smem + KOFF + t * 512 + px * 2) = (_Float16)__expf(-0.5f * ss);
                }
                ++t;
            }
        }
    }
    __syncthreads();
    const int lane = tid & 63;
    const int l15 = lane & 15, kg = lane >> 4;
    const int wv = tid >> 6;
    const int st0 = wv * 32, st1 = st0 + 16;
    const int r0 = wv >> 1;
    const int c00 = (wv & 1) * 32;
    f4 acc0 = {0.f, 0.f, 0.f, 0.f}, acc1 = {0.f, 0.f, 0.f, 0.f};
    const unsigned char* xg = smem + XOFF + kg * XJG;
    const float bv = bias[half * 16 + l15];
    int t = 0;
#pragma unroll
    for (int k = 0; k < KK; ++k) {
#pragma unroll
        for (int l = 0; l < KK; ++l) {
            const int abase = ((r0 + k) * PRW + c00 + l + l15) * 16;
            h8 A0 = *(const h8*)(xg + abase);
            h8 A1 = *(const h8*)(xg + abase + 256);
            h8 Bv = *(const h8*)(smem + WOFF + t * 1024 + kg * 256 + l15 * 16);
            f4 p0 = __builtin_amdgcn_mfma_f32_16x16x32_f16(A0, Bv, (f4){0.f,0.f,0.f,0.f}, 0, 0, 0);
            f4 p1 = __builtin_amdgcn_mfma_f32_16x16x32_f16(A1, Bv, (f4){0.f,0.f,0.f,0.f}, 0, 0, 0);
            h4v k0 = *(const h4v*)(smem + KOFF + t * 512 + (st0 + kg * 4) * 2);
            h4v k1 = *(const h4v*)(smem + KOFF + t * 512 + (st1 + kg * 4) * 2);
#pragma unroll
            for (int i = 0; i < 4; ++i) {
                acc0[i] = fmaf((float)k0[i], p0[i], acc0[i]);
                acc1[i] = fmaf((float)k1[i], p1[i], acc1[i]);
            }
            ++t;
        }
    }
#pragma unroll
    for (int i = 0; i < 4; ++i) { acc0[i] += bv; acc1[i] += bv; }
    __syncthreads();
    float* outst = (float*)smem;
    *(f4*)(outst + l15 * 260 + st0 + kg * 4) = acc0;
    *(f4*)(outst + l15 * 260 + st1 + kg * 4) = acc1;
    __syncthreads();
    const int o = tid >> 5;
    const int p = (tid & 31) * 8;
    f4 v0 = *(const f4*)(outst + o * 260 + p);
    f4 v1 = *(const f4*)(outst + o * 260 + p + 4);
    const int mr = p >> 6, nc = p & 63;
    float* op = out + ((size_t)(bz * COUT + half * 16 + o)) * HW + (size_t)(tm + mr) * Ww + tn + nc;
    *(f4*)op = v0;
    *(f4*)(op + 4) = v1;
}

extern "C" void kernel_launch(void* const* d_in, const int* in_sizes, int n_in,
                              void* d_out, int out_size, void* d_ws, size_t ws_size,
                              hipStream_t stream) {
    const float* x      = (const float*)d_in[0];
    const float* guide  = (const float*)d_in[1];
    const float* weight = (const float*)d_in[2];
    const float* bias   = (const float*)d_in[3];
    float* out = (float*)d_out;

    if (ws_size >= (size_t)WS_NEED) {
        _Float16* xt = (_Float16*)((char*)d_ws + XT_OFF);
        _Float16* wt = (_Float16*)((char*)d_ws + WT_OFF);
        _Float16* gt = (_Float16*)((char*)d_ws + GT_OFF);
        prep<<<dim3(690), 512, 0, stream>>>(x, guide, weight, xt, wt, gt);
        pac_mfma9<<<dim3(128, Bn), 256, 0, stream>>>(xt, wt, gt, bias, out);
    } else {
        pac_mfma2<<<dim3(64, 2, Bn), 512, 0, stream>>>(x, guide, weight, bias, out);
    }
}

// Round 16
// 23.567 us; speedup vs baseline: 1.1517x; 1.1517x over previous
//
#include <hip/hip_runtime.h>

#define Bn   4
#define CIN  32
#define COUT 32
#define CG   8
#define Hh   128
#define Ww   128
#define KK   5
#define HW   (Hh * Ww)

#define TW   64     // tile 64 wide x 4 tall = 256 px per block
#define TH   4
#define PRW  68     // halo 68 x 8
#define PRH  8
#define NSLOT (PRW * PRH)   // 544

#define PADW 132    // padded xt2 spatial dim (2-px zero border)

typedef _Float16 h8  __attribute__((ext_vector_type(8)));
typedef _Float16 h2  __attribute__((ext_vector_type(2)));
typedef float    f4  __attribute__((ext_vector_type(4)));

// main LDS layout (bytes) — SoA over j-octets (16B lane stride on fragment reads):
//   x:    [4 jg][544 slots] h8            : 34816  (34 x 1KB DMA chunks)
//   w h0: [25 t][4 jg][16 o] h8           : 25600  (25 x 1KB DMA chunks)
//   kern: [25 t][8 g][16 i] u32-pairs     : 12800
#define XOFF  0
#define XJG   8704
#define WOFF  34816
#define KOFF  60416
#define SMEMB 73216

// workspace (bytes): xt2 padded [4 b][132][132][4 jg] h8
#define XT_OFF 0                       // 4*132*132*4*16 = 4,460,544
#define WT_OFF 4460544                 // 25600*2        =    51,200
#define GT_OFF 4511744                 // 4*16384*8*2    = 1,048,576
#define WS_NEED 5560320

#define GLDS(gp, lp) __builtin_amdgcn_global_load_lds( \
    (const __attribute__((address_space(1))) void*)(gp), \
    (__attribute__((address_space(3))) void*)(lp), 16, 0, 0)

// ---------- pre-pass: x (padded) / w / guide transforms + border zero ----------
__global__ __launch_bounds__(512) void prep(
    const float* __restrict__ x, const float* __restrict__ guide,
    const float* __restrict__ w,
    _Float16* __restrict__ xt, _Float16* __restrict__ wt, _Float16* __restrict__ gt)
{
    const int bid = blockIdx.x;
    const int tid = threadIdx.x;

    if (bid < 512) {
        // x[b][j][m][n] f32 -> xt2[b][m+2][n+2][32j] f16 (padded)
        const int b = bid >> 7, m = bid & 127;
        const int n = tid & 127, jh = tid >> 7;
        const float* xp = x + ((size_t)(b * CIN + jh * 8)) * HW + m * Ww + n;
        h8 v;
#pragma unroll
        for (int e = 0; e < 8; ++e) v[e] = (_Float16)xp[(size_t)e * HW];
        ((h8*)xt)[(((size_t)b * PADW + m + 2) * PADW + n + 2) * 4 + jh] = v;
    } else if (bid < 562) {
        // w -> wt[half][t][jg][o][e] f16 (LDS image)
        const int idx = (bid - 512) * 512 + tid;
        const int ht = idx >> 9;
        const int half = ht / 25, t = ht - half * 25;
        const int rem = idx & 511;
        const int jg = rem >> 7, o = (rem >> 3) & 15, e = rem & 7;
        wt[idx] = (_Float16)w[(size_t)(half * 16 + o) * (CIN * KK * KK) + (jg * 8 + e) * (KK * KK) + t];
    } else if (bid < 690) {
        // guide[b][c][m][n] f32 -> gt[b][m][n][8c] f16
        const int gr = (bid - 562) * 4 + (tid >> 7);
        const int b = gr >> 7, m = gr & 127;
        const int n = tid & 127;
        const float* gp = guide + ((size_t)b * CG) * HW + m * Ww + n;
        h8 v;
#pragma unroll
        for (int e = 0; e < 8; ++e) v[e] = (_Float16)gp[(size_t)e * HW];
        ((h8*)gt)[(size_t)b * HW + m * Ww + n] = v;
    } else {
        // zero xt2's 2-px border: 1040 border px per batch x 4 batches = 4160
        const int idx = (bid - 690) * 512 + tid;
        if (idx < 4160) {
            const int b = idx / 1040, r = idx - b * 1040;
            int mp, np;
            if (r < 528) {                      // rows {0,1,130,131}, full width
                const int mr = r / 132;
                mp = (mr < 2) ? mr : mr + 128;
                np = r - mr * 132;
            } else {                            // rows 2..129, cols {0,1,130,131}
                const int r2 = r - 528;
                mp = 2 + (r2 >> 2);
                const int q = r2 & 3;
                np = (q < 2) ? q : q + 128;
            }
            h8 z = {};
            h8* dst = (h8*)xt + (((size_t)b * PADW + mp) * PADW + np) * 4;
            dst[0] = z; dst[1] = z; dst[2] = z; dst[3] = z;
        }
    }
}

// ---------- main: R13 structure, staging via async global_load_lds DMA ----------
__global__ __launch_bounds__(512, 2) void pac_mfma10(
    const _Float16* __restrict__ xt, const _Float16* __restrict__ wt,
    const _Float16* __restrict__ gt, const float* __restrict__ bias,
    float* __restrict__ out)
{
    __shared__ __align__(16) unsigned char smem[SMEMB];

    const int tid = threadIdx.x;
    const int bx  = blockIdx.x;        // 0..63 spatial tiles (2 wide x 32 tall)
    const int bz  = blockIdx.y;        // batch
    const int tm = (bx >> 1) * TH;
    const int tn = (bx & 1) * TW;

    const int lane = tid & 63;
    const int l15 = lane & 15, kg = lane >> 4;
    const int wv = tid >> 6;           // 8 waves

    // ---- issue x staging DMA: 34 chunks of 1KB (dest = linear [jg][slot]) ----
    // padded xt2: halo row r -> m' = tm + r (border +2 cancels -2)
    for (int c = wv; c < 34; c += 8) {
        const int i = c * 64 + lane;
        const int jg = i / NSLOT;
        const int slot = i - jg * NSLOT;
        const int r = slot / PRW, cc = slot - r * PRW;
        const _Float16* g = xt +
            ((((size_t)bz * PADW + tm + r) * PADW + tn + cc) * 4 + jg) * 8;
        GLDS(g, smem + XOFF + c * 1024);
    }

    // ---- issue w half0 staging DMA: 25 chunks, pure linear copy ----
    for (int c = wv; c < 25; c += 8) {
        const _Float16* g = wt + (c * 64 + lane) * 8;
        GLDS(g, smem + WOFF + c * 1024);
    }

    // ---- preload half1 B-fragments (global wt, L2-hot) ----
    const h8* wh1 = (const h8*)wt + 1600;
    h8 B1r[25];
#pragma unroll
    for (int t = 0; t < 25; ++t)
        B1r[t] = wh1[t * 64 + kg * 16 + l15];

    // ---- kern compute (VALU + gt loads) overlaps the staging DMA ----
    {
        const int px = tid & 255, th = tid >> 8;   // th=0: taps 0..12, th=1: 13..24
        const int pr = px >> 6, pc = px & 63;
        const int pg = px >> 5, ps = (px >> 4) & 1, pi = px & 15;
        const int m = tm + pr, n = tn + pc;
        const h8* gtb = (const h8*)gt + (size_t)bz * HW;
        const h8 c8 = gtb[m * Ww + n];
        float cg[8];
#pragma unroll
        for (int i = 0; i < 8; ++i) cg[i] = (float)c8[i];
        int t = 0;
#pragma unroll
        for (int k = 0; k < KK; ++k) {
#pragma unroll
            for (int l = 0; l < KK; ++l) {
                if ((t < 13) == (th == 0)) {
                    const int gm = m + k - 2, gn = n + l - 2;
                    h8 gv = {};
                    if ((unsigned)gm < (unsigned)Hh && (unsigned)gn < (unsigned)Ww)
                        gv = gtb[gm * Ww + gn];
                    float ss = 0.f;
#pragma unroll
                    for (int i = 0; i < 8; ++i) {
                        const float d = (float)gv[i] - cg[i];
                        ss = fmaf(d, d, ss);
                    }
                    *(_Float16*)(smem + KOFF + t * 512 + ((pg * 16 + pi) * 2 + ps) * 2) =
                        (_Float16)__expf(-0.5f * ss);
                }
                ++t;
            }
        }
    }

    __syncthreads();   // drains DMA (vmcnt 0) + kern writes

    // ---- main loop: scale A once, 4 MFMA chains (2 subtiles x 2 o-halves) ----
    const int st0 = wv * 32, st1 = st0 + 16;
    const int r0 = wv >> 1;
    const int c00 = (wv & 1) * 32;

    f4 acc00 = {0.f,0.f,0.f,0.f}, acc01 = {0.f,0.f,0.f,0.f};
    f4 acc10 = {0.f,0.f,0.f,0.f}, acc11 = {0.f,0.f,0.f,0.f};
    const unsigned char* xg = smem + XOFF + kg * XJG;
    const int kbase = KOFF + (wv * 16 + l15) * 4;

    int t = 0;
#pragma unroll
    for (int k = 0; k < KK; ++k) {
#pragma unroll
        for (int l = 0; l < KK; ++l) {
            const int abase = ((r0 + k) * PRW + c00 + l + l15) * 16;
            h8 A0 = *(const h8*)(xg + abase);
            h8 A1 = *(const h8*)(xg + abase + 256);
            h8 B0 = *(const h8*)(smem + WOFF + t * 1024 + kg * 256 + l15 * 16);
            h2 kk = *(const h2*)(smem + kbase + t * 512);

            h8 A0s = A0 * kk[0];
            h8 A1s = A1 * kk[1];

            acc00 = __builtin_amdgcn_mfma_f32_16x16x32_f16(A0s, B0,     acc00, 0, 0, 0);
            acc01 = __builtin_amdgcn_mfma_f32_16x16x32_f16(A0s, B1r[t], acc01, 0, 0, 0);
            acc10 = __builtin_amdgcn_mfma_f32_16x16x32_f16(A1s, B0,     acc10, 0, 0, 0);
            acc11 = __builtin_amdgcn_mfma_f32_16x16x32_f16(A1s, B1r[t], acc11, 0, 0, 0);
            ++t;
        }
    }

    const float bv0 = bias[l15], bv1 = bias[16 + l15];
#pragma unroll
    for (int i = 0; i < 4; ++i) {
        acc00[i] += bv0; acc10[i] += bv0;
        acc01[i] += bv1; acc11[i] += bv1;
    }

    // ---- transpose through LDS (aliases x region) for dense stores ----
    __syncthreads();
    float* outst = (float*)smem;               // [32 o][260 px]
    *(f4*)(outst + l15 * 260 + st0 + kg * 4) = acc00;
    *(f4*)(outst + l15 * 260 + st1 + kg * 4) = acc10;
    *(f4*)(outst + (16 + l15) * 260 + st0 + kg * 4) = acc01;
    *(f4*)(outst + (16 + l15) * 260 + st1 + kg * 4) = acc11;
    __syncthreads();

    const int o = tid >> 4;
    const int i = tid & 15;
    float* op = out + ((size_t)(bz * COUT + o)) * HW;
#pragma unroll
    for (int c = 0; c < 4; ++c) {
        f4 v = *(const f4*)(outst + o * 260 + c * 64 + i * 4);
        *(f4*)(op + (size_t)(tm + c) * Ww + tn + i * 4) = v;
    }
}

// ---------- fallback (R6 kernel, used only if ws_size too small) ----------
typedef _Float16 h4v __attribute__((ext_vector_type(4)));
__global__ __launch_bounds__(512, 4) void pac_mfma2(
    const float* __restrict__ x, const float* __restrict__ guide,
    const float* __restrict__ weight, const float* __restrict__ bias,
    float* __restrict__ out)
{
    __shared__ __align__(16) unsigned char smem[SMEMB];
    const int tid  = threadIdx.x;
    const int bx   = blockIdx.x;
    const int half = blockIdx.y;
    const int bz   = blockIdx.z;
    const int tm = (bx >> 1) * TH;
    const int tn = (bx & 1) * TW;

    const float* xb = x + (size_t)bz * CIN * HW;
#pragma unroll
    for (int it = 0; it < 34; ++it) {
        const int idx  = it * 512 + tid;
        const int j    = idx / NSLOT;
        const int slot = idx - j * NSLOT;
        const int r    = slot / PRW;
        const int c    = slot - r * PRW;
        const int gm = tm + r - 2, gn = tn + c - 2;
        float v = 0.f;
        if ((unsigned)gm < (unsigned)Hh && (unsigned)gn < (unsigned)Ww)
            v = xb[(size_t)j * HW + gm * Ww + gn];
        *(_Float16*)(smem + XOFF + (j >> 3) * XJG + slot * 16 + (j & 7) * 2) = (_Float16)v;
    }
#pragma unroll
    for (int it = 0; it < 25; ++it) {
        const int idx = it * 512 + tid;
        const int o = idx & 15;
        const int j = (idx >> 4) & 31;
        const int t = idx >> 9;
        const float v = weight[(size_t)(half * 16 + o) * (CIN * KK * KK) + j * (KK * KK) + t];
        *(_Float16*)(smem + WOFF + t * 1024 + (j >> 3) * 256 + o * 16 + (j & 7) * 2) = (_Float16)v;
    }
    {
        const int px = tid & 255, th = tid >> 8;
        const int pr = px >> 6, pc = px & 63;
        const int m = tm + pr, n = tn + pc;
        const float* gb = guide + ((size_t)bz * CG) * HW + m * Ww + n;
        float center[CG];
#pragma unroll
        for (int c = 0; c < CG; ++c) center[c] = gb[c * HW];
        int t = 0;
#pragma unroll
        for (int k = 0; k < KK; ++k) {
            const int dm = k - 2;
            const bool rowok = ((unsigned)(m + dm) < (unsigned)Hh);
#pragma unroll
            for (int l = 0; l < KK; ++l) {
                if ((t < 13) == (th == 0)) {
                    const int dn = l - 2;
                    const bool ok = rowok && ((unsigned)(n + dn) < (unsigned)Ww);
                    float ss = 0.f;
#pragma unroll
                    for (int c = 0; c < CG; ++c) {
                        float gv = ok ? gb[c * HW + dm * Ww + dn] : 0.f;
                        float d = gv - center[c];
                        ss = fmaf(d, d, ss);
                    }
                    *(_Float16*)(smem + KOFF + t * 512 + px * 2) = (_Float16)__expf(-0.5f * ss);
                }
                ++t;
            }
        }
    }
    __syncthreads();
    const int lane = tid & 63;
    const int l15 = lane & 15, kg = lane >> 4;
    const int wv = tid >> 6;
    const int st0 = wv * 32, st1 = st0 + 16;
    const int r0 = wv >> 1;
    const int c00 = (wv & 1) * 32;
    f4 acc0 = {0.f, 0.f, 0.f, 0.f}, acc1 = {0.f, 0.f, 0.f, 0.f};
    const unsigned char* xg = smem + XOFF + kg * XJG;
    const float bv = bias[half * 16 + l15];
    int t = 0;
#pragma unroll
    for (int k = 0; k < KK; ++k) {
#pragma unroll
        for (int l = 0; l < KK; ++l) {
            const int abase = ((r0 + k) * PRW + c00 + l + l15) * 16;
            h8 A0 = *(const h8*)(xg + abase);
            h8 A1 = *(const h8*)(xg + abase + 256);
            h8 Bv = *(const h8*)(smem + WOFF + t * 1024 + kg * 256 + l15 * 16);
            f4 p0 = __builtin_amdgcn_mfma_f32_16x16x32_f16(A0, Bv, (f4){0.f,0.f,0.f,0.f}, 0, 0, 0);
            f4 p1 = __builtin_amdgcn_mfma_f32_16x16x32_f16(A1, Bv, (f4){0.f,0.f,0.f,0.f}, 0, 0, 0);
            h4v k0 = *(const h4v*)(smem + KOFF + t * 512 + (st0 + kg * 4) * 2);
            h4v k1 = *(const h4v*)(smem + KOFF + t * 512 + (st1 + kg * 4) * 2);
#pragma unroll
            for (int i = 0; i < 4; ++i) {
                acc0[i] = fmaf((float)k0[i], p0[i], acc0[i]);
                acc1[i] = fmaf((float)k1[i], p1[i], acc1[i]);
            }
            ++t;
        }
    }
#pragma unroll
    for (int i = 0; i < 4; ++i) { acc0[i] += bv; acc1[i] += bv; }
    __syncthreads();
    float* outst = (float*)smem;
    *(f4*)(outst + l15 * 260 + st0 + kg * 4) = acc0;
    *(f4*)(outst + l15 * 260 + st1 + kg * 4) = acc1;
    __syncthreads();
    const int o = tid >> 5;
    const int p = (tid & 31) * 8;
    f4 v0 = *(const f4*)(outst + o * 260 + p);
    f4 v1 = *(const f4*)(outst + o * 260 + p + 4);
    const int mr = p >> 6, nc = p & 63;
    float* op = out + ((size_t)(bz * COUT + half * 16 + o)) * HW + (size_t)(tm + mr) * Ww + tn + nc;
    *(f4*)op = v0;
    *(f4*)(op + 4) = v1;
}

extern "C" void kernel_launch(void* const* d_in, const int* in_sizes, int n_in,
                              void* d_out, int out_size, void* d_ws, size_t ws_size,
                              hipStream_t stream) {
    const float* x      = (const float*)d_in[0];
    const float* guide  = (const float*)d_in[1];
    const float* weight = (const float*)d_in[2];
    const float* bias   = (const float*)d_in[3];
    float* out = (float*)d_out;

    if (ws_size >= (size_t)WS_NEED) {
        _Float16* xt = (_Float16*)((char*)d_ws + XT_OFF);
        _Float16* wt = (_Float16*)((char*)d_ws + WT_OFF);
        _Float16* gt = (_Float16*)((char*)d_ws + GT_OFF);
        prep<<<dim3(699), 512, 0, stream>>>(x, guide, weight, xt, wt, gt);
        pac_mfma10<<<dim3(64, Bn), 512, 0, stream>>>(xt, wt, gt, bias, out);
    } else {
        pac_mfma2<<<dim3(64, 2, Bn), 512, 0, stream>>>(x, guide, weight, bias, out);
    }
}

// Round 17
// 23.417 us; speedup vs baseline: 1.1590x; 1.0064x over previous
//
#include <hip/hip_runtime.h>

#define Bn   4
#define CIN  32
#define COUT 32
#define CG   8
#define Hh   128
#define Ww   128
#define KK   5
#define HW   (Hh * Ww)

#define TW   64     // tile 64 wide x 4 tall = 256 px per block
#define TH   4
#define PRW  68     // halo 68 x 8
#define PRH  8
#define NSLOT (PRW * PRH)   // 544

#define PADW 132    // padded xt2 spatial dim (2-px zero border)

typedef _Float16 h8  __attribute__((ext_vector_type(8)));
typedef float    f4  __attribute__((ext_vector_type(4)));

// main LDS layout (bytes) — SoA over j-octets (16B lane stride on fragment reads):
//   x:    [4 jg][544 slots] h8            : 34816  (34 x 1KB DMA chunks)
//   w:    [2 half][25 t][4 jg][16 o] h8   : 51200  (50 x 1KB DMA chunks)
//   kern: [25 t][256 px] f16              : 12800
#define XOFF  0
#define XJG   8704
#define WOFF  34816
#define KOFF  86016
#define SMEMB 98816

// workspace (bytes): xt2 padded [4 b][132][132][4 jg] h8
#define XT_OFF 0                       // 4*132*132*4*16 = 4,460,544
#define WT_OFF 4460544                 // 25600*2        =    51,200
#define GT_OFF 4511744                 // 4*16384*8*2    = 1,048,576
#define WS_NEED 5560320

#define GLDS(gp, lp) __builtin_amdgcn_global_load_lds( \
    (const __attribute__((address_space(1))) void*)(gp), \
    (__attribute__((address_space(3))) void*)(lp), 16, 0, 0)

// ---------- pre-pass: x (padded) / w / guide transforms + border zero ----------
__global__ __launch_bounds__(512) void prep(
    const float* __restrict__ x, const float* __restrict__ guide,
    const float* __restrict__ w,
    _Float16* __restrict__ xt, _Float16* __restrict__ wt, _Float16* __restrict__ gt)
{
    const int bid = blockIdx.x;
    const int tid = threadIdx.x;

    if (bid < 512) {
        // x[b][j][m][n] f32 -> xt2[b][m+2][n+2][32j] f16 (padded)
        const int b = bid >> 7, m = bid & 127;
        const int n = tid & 127, jh = tid >> 7;
        const float* xp = x + ((size_t)(b * CIN + jh * 8)) * HW + m * Ww + n;
        h8 v;
#pragma unroll
        for (int e = 0; e < 8; ++e) v[e] = (_Float16)xp[(size_t)e * HW];
        ((h8*)xt)[(((size_t)b * PADW + m + 2) * PADW + n + 2) * 4 + jh] = v;
    } else if (bid < 562) {
        // w -> wt[half][t][jg][o][e] f16 (LDS image)
        const int idx = (bid - 512) * 512 + tid;
        const int ht = idx >> 9;
        const int half = ht / 25, t = ht - half * 25;
        const int rem = idx & 511;
        const int jg = rem >> 7, o = (rem >> 3) & 15, e = rem & 7;
        wt[idx] = (_Float16)w[(size_t)(half * 16 + o) * (CIN * KK * KK) + (jg * 8 + e) * (KK * KK) + t];
    } else if (bid < 690) {
        // guide[b][c][m][n] f32 -> gt[b][m][n][8c] f16
        const int gr = (bid - 562) * 4 + (tid >> 7);
        const int b = gr >> 7, m = gr & 127;
        const int n = tid & 127;
        const float* gp = guide + ((size_t)b * CG) * HW + m * Ww + n;
        h8 v;
#pragma unroll
        for (int e = 0; e < 8; ++e) v[e] = (_Float16)gp[(size_t)e * HW];
        ((h8*)gt)[(size_t)b * HW + m * Ww + n] = v;
    } else {
        // zero xt2's 2-px border
        const int idx = (bid - 690) * 512 + tid;
        if (idx < 4160) {
            const int b = idx / 1040, r = idx - b * 1040;
            int mp, np;
            if (r < 528) {
                const int mr = r / 132;
                mp = (mr < 2) ? mr : mr + 128;
                np = r - mr * 132;
            } else {
                const int r2 = r - 528;
                mp = 2 + (r2 >> 2);
                const int q = r2 & 3;
                np = (q < 2) ? q : q + 128;
            }
            h8 z = {};
            h8* dst = (h8*)xt + (((size_t)b * PADW + mp) * PADW + np) * 4;
            dst[0] = z; dst[1] = z; dst[2] = z; dst[3] = z;
        }
    }
}

// ---------- main: 1024 threads (16 waves = 4/SIMD), all-LDS operands ----------
__global__ __launch_bounds__(1024, 4) void pac_mfma11(
    const _Float16* __restrict__ xt, const _Float16* __restrict__ wt,
    const _Float16* __restrict__ gt, const float* __restrict__ bias,
    float* __restrict__ out)
{
    __shared__ __align__(16) unsigned char smem[SMEMB];

    const int tid = threadIdx.x;
    const int bx  = blockIdx.x;        // 0..63 spatial tiles (2 wide x 32 tall)
    const int bz  = blockIdx.y;        // batch
    const int tm = (bx >> 1) * TH;
    const int tn = (bx & 1) * TW;

    const int lane = tid & 63;
    const int l15 = lane & 15, kg = lane >> 4;
    const int wv = tid >> 6;           // 16 waves

    // ---- issue x staging DMA: 34 chunks of 1KB (dest linear [jg][slot]) ----
    for (int c = wv; c < 34; c += 16) {
        const int i = c * 64 + lane;
        const int jg = i / NSLOT;
        const int slot = i - jg * NSLOT;
        const int r = slot / PRW, cc = slot - r * PRW;
        const _Float16* g = xt +
            ((((size_t)bz * PADW + tm + r) * PADW + tn + cc) * 4 + jg) * 8;
        GLDS(g, smem + XOFF + c * 1024);
    }

    // ---- issue w staging DMA: both halves, 50 chunks, pure linear copy ----
    for (int c = wv; c < 50; c += 16) {
        const _Float16* g = wt + (c * 64 + lane) * 8;
        GLDS(g, smem + WOFF + c * 1024);
    }

    // ---- kern compute (overlaps DMA): 4 thread-groups split the 25 taps ----
    {
        const int px = tid & 255, th = tid >> 8;   // th = 0..3
        const int lo = (th * 25) >> 2, hi = ((th + 1) * 25) >> 2;  // 6/6/6/7 taps
        const int pr = px >> 6, pc = px & 63;
        const int m = tm + pr, n = tn + pc;
        const h8* gtb = (const h8*)gt + (size_t)bz * HW;
        const h8 c8 = gtb[m * Ww + n];
        float cg[8];
#pragma unroll
        for (int i = 0; i < 8; ++i) cg[i] = (float)c8[i];
        int t = 0;
#pragma unroll
        for (int k = 0; k < KK; ++k) {
#pragma unroll
            for (int l = 0; l < KK; ++l) {
                if (t >= lo && t < hi) {
                    const int gm = m + k - 2, gn = n + l - 2;
                    h8 gv = {};
                    if ((unsigned)gm < (unsigned)Hh && (unsigned)gn < (unsigned)Ww)
                        gv = gtb[gm * Ww + gn];
                    float ss = 0.f;
#pragma unroll
                    for (int i = 0; i < 8; ++i) {
                        const float d = (float)gv[i] - cg[i];
                        ss = fmaf(d, d, ss);
                    }
                    *(_Float16*)(smem + KOFF + t * 512 + px * 2) =
                        (_Float16)__expf(-0.5f * ss);
                }
                ++t;
            }
        }
    }

    __syncthreads();   // drains DMA + kern writes

    // ---- main loop: per wave one 16-px subtile, 2 o-half MFMA chains ----
    const int st0 = wv * 16;                   // px base
    const int r0 = wv >> 2;                    // tile row 0..3
    const int c0 = (wv & 3) * 16;              // col base 0/16/32/48

    f4 acc0 = {0.f,0.f,0.f,0.f}, acc1 = {0.f,0.f,0.f,0.f};
    const unsigned char* xg = smem + XOFF + kg * XJG;

    int t = 0;
#pragma unroll
    for (int k = 0; k < KK; ++k) {
#pragma unroll
        for (int l = 0; l < KK; ++l) {
            const int abase = ((r0 + k) * PRW + c0 + l + l15) * 16;
            h8 A0 = *(const h8*)(xg + abase);
            h8 B0 = *(const h8*)(smem + WOFF + t * 1024 + kg * 256 + l15 * 16);
            h8 B1 = *(const h8*)(smem + WOFF + 25600 + t * 1024 + kg * 256 + l15 * 16);
            const _Float16 kk = *(const _Float16*)(smem + KOFF + t * 512 + (st0 + l15) * 2);

            h8 A0s = A0 * kk;                          // 4x v_pk_mul_f16, used twice

            acc0 = __builtin_amdgcn_mfma_f32_16x16x32_f16(A0s, B0, acc0, 0, 0, 0);
            acc1 = __builtin_amdgcn_mfma_f32_16x16x32_f16(A0s, B1, acc1, 0, 0, 0);
            ++t;
        }
    }

    const float bv0 = bias[l15], bv1 = bias[16 + l15];
#pragma unroll
    for (int i = 0; i < 4; ++i) { acc0[i] += bv0; acc1[i] += bv1; }

    // ---- transpose through LDS (aliases x region) for dense stores ----
    __syncthreads();
    float* outst = (float*)smem;               // [32 o][260 px] = 33280 B
    *(f4*)(outst + l15 * 260 + st0 + kg * 4) = acc0;
    *(f4*)(outst + (16 + l15) * 260 + st0 + kg * 4) = acc1;
    __syncthreads();

    const int o = tid >> 5;                    // 0..31
    const int p = (tid & 31) * 8;              // 0..248
    const int row = p >> 6, col = p & 63;
    float* op = out + ((size_t)(bz * COUT + o)) * HW + (size_t)(tm + row) * Ww + tn + col;
    const float* src = outst + o * 260 + p;
    *(f4*)op = *(const f4*)src;
    *(f4*)(op + 4) = *(const f4*)(src + 4);
}

// ---------- fallback (R6 kernel, used only if ws_size too small) ----------
typedef _Float16 h4v __attribute__((ext_vector_type(4)));
#define FXOFF  0
#define FXJG   8704
#define FWOFF  34816
#define FKOFF  60416
__global__ __launch_bounds__(512, 4) void pac_mfma2(
    const float* __restrict__ x, const float* __restrict__ guide,
    const float* __restrict__ weight, const float* __restrict__ bias,
    float* __restrict__ out)
{
    __shared__ __align__(16) unsigned char smem[73216];
    const int tid  = threadIdx.x;
    const int bx   = blockIdx.x;
    const int half = blockIdx.y;
    const int bz   = blockIdx.z;
    const int tm = (bx >> 1) * TH;
    const int tn = (bx & 1) * TW;

    const float* xb = x + (size_t)bz * CIN * HW;
#pragma unroll
    for (int it = 0; it < 34; ++it) {
        const int idx  = it * 512 + tid;
        const int j    = idx / NSLOT;
        const int slot = idx - j * NSLOT;
        const int r    = slot / PRW;
        const int c    = slot - r * PRW;
        const int gm = tm + r - 2, gn = tn + c - 2;
        float v = 0.f;
        if ((unsigned)gm < (unsigned)Hh && (unsigned)gn < (unsigned)Ww)
            v = xb[(size_t)j * HW + gm * Ww + gn];
        *(_Float16*)(smem + FXOFF + (j >> 3) * FXJG + slot * 16 + (j & 7) * 2) = (_Float16)v;
    }
#pragma unroll
    for (int it = 0; it < 25; ++it) {
        const int idx = it * 512 + tid;
        const int o = idx & 15;
        const int j = (idx >> 4) & 31;
        const int t = idx >> 9;
        const float v = weight[(size_t)(half * 16 + o) * (CIN * KK * KK) + j * (KK * KK) + t];
        *(_Float16*)(smem + FWOFF + t * 1024 + (j >> 3) * 256 + o * 16 + (j & 7) * 2) = (_Float16)v;
    }
    {
        const int px = tid & 255, th = tid >> 8;
        const int pr = px >> 6, pc = px & 63;
        const int m = tm + pr, n = tn + pc;
        const float* gb = guide + ((size_t)bz * CG) * HW + m * Ww + n;
        float center[CG];
#pragma unroll
        for (int c = 0; c < CG; ++c) center[c] = gb[c * HW];
        int t = 0;
#pragma unroll
        for (int k = 0; k < KK; ++k) {
            const int dm = k - 2;
            const bool rowok = ((unsigned)(m + dm) < (unsigned)Hh);
#pragma unroll
            for (int l = 0; l < KK; ++l) {
                if ((t < 13) == (th == 0)) {
                    const int dn = l - 2;
                    const bool ok = rowok && ((unsigned)(n + dn) < (unsigned)Ww);
                    float ss = 0.f;
#pragma unroll
                    for (int c = 0; c < CG; ++c) {
                        float gv = ok ? gb[c * HW + dm * Ww + dn] : 0.f;
                        float d = gv - center[c];
                        ss = fmaf(d, d, ss);
                    }
                    *(_Float16*)(smem + FKOFF + t * 512 + px * 2) = (_Float16)__expf(-0.5f * ss);
                }
                ++t;
            }
        }
    }
    __syncthreads();
    const int lane = tid & 63;
    const int l15 = lane & 15, kg = lane >> 4;
    const int wv = tid >> 6;
    const int st0 = wv * 32, st1 = st0 + 16;
    const int r0 = wv >> 1;
    const int c00 = (wv & 1) * 32;
    f4 acc0 = {0.f, 0.f, 0.f, 0.f}, acc1 = {0.f, 0.f, 0.f, 0.f};
    const unsigned char* xg = smem + FXOFF + kg * FXJG;
    const float bv = bias[half * 16 + l15];
    int t = 0;
#pragma unroll
    for (int k = 0; k < KK; ++k) {
#pragma unroll
        for (int l = 0; l < KK; ++l) {
            const int abase = ((r0 + k) * PRW + c00 + l + l15) * 16;
            h8 A0 = *(const h8*)(xg + abase);
            h8 A1 = *(const h8*)(xg + abase + 256);
            h8 Bv = *(const h8*)(smem + FWOFF + t * 1024 + kg * 256 + l15 * 16);
            f4 p0 = __builtin_amdgcn_mfma_f32_16x16x32_f16(A0, Bv, (f4){0.f,0.f,0.f,0.f}, 0, 0, 0);
            f4 p1 = __builtin_amdgcn_mfma_f32_16x16x32_f16(A1, Bv, (f4){0.f,0.f,0.f,0.f}, 0, 0, 0);
            h4v k0 = *(const h4v*)(smem + FKOFF + t * 512 + (st0 + kg * 4) * 2);
            h4v k1 = *(const h4v*)(smem + FKOFF + t * 512 + (st1 + kg * 4) * 2);
#pragma unroll
            for (int i = 0; i < 4; ++i) {
                acc0[i] = fmaf((float)k0[i], p0[i], acc0[i]);
                acc1[i] = fmaf((float)k1[i], p1[i], acc1[i]);
            }
            ++t;
        }
    }
#pragma unroll
    for (int i = 0; i < 4; ++i) { acc0[i] += bv; acc1[i] += bv; }
    __syncthreads();
    float* outst = (float*)smem;
    *(f4*)(outst + l15 * 260 + st0 + kg * 4) = acc0;
    *(f4*)(outst + l15 * 260 + st1 + kg * 4) = acc1;
    __syncthreads();
    const int o = tid >> 5;
    const int p = (tid & 31) * 8;
    f4 v0 = *(const f4*)(outst + o * 260 + p);
    f4 v1 = *(const f4*)(outst + o * 260 + p + 4);
    const int mr = p >> 6, nc = p & 63;
    float* op = out + ((size_t)(bz * COUT + half * 16 + o)) * HW + (size_t)(tm + mr) * Ww + tn + nc;
    *(f4*)op = v0;
    *(f4*)(op + 4) = v1;
}

extern "C" void kernel_launch(void* const* d_in, const int* in_sizes, int n_in,
                              void* d_out, int out_size, void* d_ws, size_t ws_size,
                              hipStream_t stream) {
    const float* x      = (const float*)d_in[0];
    const float* guide  = (const float*)d_in[1];
    const float* weight = (const float*)d_in[2];
    const float* bias   = (const float*)d_in[3];
    float* out = (float*)d_out;

    if (ws_size >= (size_t)WS_NEED) {
        _Float16* xt = (_Float16*)((char*)d_ws + XT_OFF);
        _Float16* wt = (_Float16*)((char*)d_ws + WT_OFF);
        _Float16* gt = (_Float16*)((char*)d_ws + GT_OFF);
        prep<<<dim3(699), 512, 0, stream>>>(x, guide, weight, xt, wt, gt);
        pac_mfma11<<<dim3(64, Bn), 1024, 0, stream>>>(xt, wt, gt, bias, out);
    } else {
        pac_mfma2<<<dim3(64, 2, Bn), 512, 0, stream>>>(x, guide, weight, bias, out);
    }
}